// Round 8
// baseline (221.998 us; speedup 1.0000x reference)
//
#include <hip/hip_runtime.h>
#include <stdint.h>

// B=2, L=2048, DM=1024, H=16, D=64
// ws layout (50 MB exactly):
//   xb    bf16[4096][1024]   x converted           (reused as arb after proj GEMM)
//   wcatT bf16[4096][1024]   [wq*0.125*log2e|wk|wqr|wkr]^T
//   qcat  bf16[4096][3072]   q|k|qr col blocks (stride 3072)
//   krT   bf16[32*64][2048]  kr transposed [b*1024+h*64+d][l] — written DIRECTLY
//                            by the proj GEMM epilogue (bn>=3072 tiles)
//   wotT  bf16[1024][1024]   wo^T

typedef __attribute__((ext_vector_type(4))) float floatx4;
typedef __attribute__((ext_vector_type(8))) short shortx8;
typedef __attribute__((ext_vector_type(4))) short shortx4;

__device__ __forceinline__ unsigned short f2bf(float f) {
    unsigned u = __float_as_uint(f);
    u += 0x7fffu + ((u >> 16) & 1u);   // RNE
    return (unsigned short)(u >> 16);
}
__device__ __forceinline__ float bf2f(unsigned short s) {
    return __uint_as_float(((unsigned)s) << 16);
}
__device__ __forceinline__ float exp2fast(float x) {
#if __has_builtin(__builtin_amdgcn_exp2f)
    return __builtin_amdgcn_exp2f(x);
#else
    return __expf(x * 0.69314718056f);
#endif
}
// pack hi16(e0),hi16(e1) -> one dword via v_perm (bf16 truncation, 1 VALU op)
__device__ __forceinline__ unsigned pkbf(float e0, float e1) {
    return __builtin_amdgcn_perm(__float_as_uint(e1), __float_as_uint(e0), 0x07060302u);
}
// PV MFMA: D += A(4 bf16, k=quad*4+i) * B(4 bf16, k=quad*4+i)
__device__ __forceinline__ floatx4 mfma16(shortx4 a, shortx4 b, floatx4 c) {
#if __has_builtin(__builtin_amdgcn_mfma_f32_16x16x16bf16_1k)
    return __builtin_amdgcn_mfma_f32_16x16x16bf16_1k(a, b, c, 0, 0, 0);
#else
    shortx8 a8 = {a[0], a[1], a[2], a[3], 0, 0, 0, 0};
    shortx8 b8 = {b[0], b[1], b[2], b[3], 0, 0, 0, 0};
    return __builtin_amdgcn_mfma_f32_16x16x32_bf16(a8, b8, c, 0, 0, 0);
#endif
}
// async global->LDS, 16B/lane; lds dest = wave-uniform base + lane*16
__device__ __forceinline__ void gll16(const void* g, void* l) {
    __builtin_amdgcn_global_load_lds(
        (const __attribute__((address_space(1))) unsigned int*)g,
        (__attribute__((address_space(3))) unsigned int*)l, 16, 0, 0);
}

// ---------- fused converts: blocks 0..4095 = x->bf16; 4096..5375 = weights ----------
__global__ __launch_bounds__(256) void k_cvt_all(const float* __restrict__ x,
                                                 const float* __restrict__ wq,
                                                 const float* __restrict__ wk,
                                                 const float* __restrict__ wqr,
                                                 const float* __restrict__ wkr,
                                                 const float* __restrict__ wo,
                                                 unsigned short* __restrict__ xb,
                                                 unsigned short* __restrict__ wcatT,
                                                 unsigned short* __restrict__ wotT) {
    __shared__ unsigned short Tl[64 * 65];
    const int t = threadIdx.x;
    if (blockIdx.x < 4096) {
        int i = (blockIdx.x * 256 + t) * 4;
        float4 v = *(const float4*)(x + i);
        ushort4 o;
        o.x = f2bf(v.x); o.y = f2bf(v.y); o.z = f2bf(v.z); o.w = f2bf(v.w);
        *(ushort4*)(xb + i) = o;
        return;
    }
    const int zz = blockIdx.x - 4096;
    const int z = zz >> 8;                       // 0..4
    const int rem = zz & 255;
    const int kt = (rem & 15) * 64, nt = (rem >> 4) * 64;
    const float* W = (z == 0) ? wq : (z == 1) ? wk : (z == 2) ? wqr : (z == 3) ? wkr : wo;
    unsigned short* outT = (z < 4) ? (wcatT + (size_t)z * 1024 * 1024) : wotT;
    // fold SDPA scale AND log2(e) into wq: scores in log2 domain, p = 2^z
    const float scale = (z == 0) ? 0.18033688f : 1.0f;   // 0.125 * 1.44269504
    {
        const int kl = t >> 3, nc = (t & 7) * 8;
        const float* src = W + (size_t)(kt + kl) * 1024 + nt + nc;
        float a[8], b[8];
        *(float4*)(a)     = *(const float4*)(src);
        *(float4*)(a + 4) = *(const float4*)(src + 4);
        *(float4*)(b)     = *(const float4*)(src + 32 * 1024);
        *(float4*)(b + 4) = *(const float4*)(src + 32 * 1024 + 4);
#pragma unroll
        for (int i = 0; i < 8; ++i) {
            Tl[kl * 65 + nc + i]        = f2bf(a[i] * scale);
            Tl[(kl + 32) * 65 + nc + i] = f2bf(b[i] * scale);
        }
    }
    __syncthreads();
    {
        const int n = t >> 2, kc = (t & 3) * 16;
        shortx8 o0, o1;
#pragma unroll
        for (int i = 0; i < 8; ++i) {
            o0[i] = (short)Tl[(kc + i) * 65 + n];
            o1[i] = (short)Tl[(kc + 8 + i) * 65 + n];
        }
        unsigned short* dst = outT + (size_t)(nt + n) * 1024 + kt + kc;
        *(shortx8*)(dst)     = o0;
        *(shortx8*)(dst + 8) = o1;
    }
}

// ---------- GEMM 256x256x(BK=64): 8-phase, 2-dbuf, counted-vmcnt pipeline ----------
// (unchanged — proven <42.4 us, refcheck'd)
__global__ __launch_bounds__(512, 1) void k_gemm_bt256(const unsigned short* __restrict__ A,
                                                       const unsigned short* __restrict__ Bt,
                                                       unsigned short* __restrict__ C,
                                                       unsigned short* __restrict__ krT,
                                                       int K) {
    __shared__ alignas(16) unsigned short As[2][256 * 64];   // 64 KiB
    __shared__ alignas(16) unsigned short Bs[2][256 * 64];   // 64 KiB
    const int t = threadIdx.x;
    const int lane = t & 63, w = t >> 6;
    const int ln = lane & 15, quad = lane >> 4;
    const int wm = w >> 2, wn = w & 3;          // 2x4 wave grid, per-wave 128x64 out
    // XCD-pinned: each XCD owns a 4x8 region of the 16x16 tile grid
    const int flat = blockIdx.x;
    const int xcd = flat & 7, idx = flat >> 3;
    const int bm = ((xcd >> 1) * 4 + (idx >> 3)) * 256;
    const int bn = ((xcd & 1) * 8 + (idx & 7)) * 256;

    floatx4 acc[8][4] = {};
    shortx8 bfr[4][2];

    // staging: wave-linear LDS dest, pre-swizzled global source chunk
    const int srow8 = w * 8 + (lane >> 3);        // 0..63
    const int sc8 = (lane & 7) ^ (lane >> 3);     // involution: chunk ^ (row&7)
    const unsigned short* gA2 = A + (size_t)(bm + srow8) * K + sc8 * 8;
    const unsigned short* gB2 = Bt + (size_t)(bn + srow8) * K + sc8 * 8;
    const int wb = w * 512;                       // wave LDS slab (shorts)

    auto stA = [&](int kt, int c, int qr) {       // qr: 0=alpha, 1=beta
        const unsigned short* s = gA2 + (size_t)(qr * 64) * K + kt * 64;
        gll16(s,                   &As[c][(qr * 64) * 64 + wb]);
        gll16(s + (size_t)128 * K, &As[c][(128 + qr * 64) * 64 + wb]);
    };
    auto stB = [&](int kt, int c, int h) {        // h: 0=rows 0-127, 1=rows 128-255
        const unsigned short* s = gB2 + (size_t)(h * 128) * K + kt * 64;
        gll16(s,                  &Bs[c][(h * 128) * 64 + wb]);
        gll16(s + (size_t)64 * K, &Bs[c][(h * 128 + 64) * 64 + wb]);
    };

    // prologue: Bt0,Bb0,Aa0,Ab0,Bt1,Bb1,Aa1 (7 half-tiles, 14 loads/wave)
    stB(0, 0, 0); stB(0, 0, 1); stA(0, 0, 0); stA(0, 0, 1);
    stB(1, 1, 0); stB(1, 1, 1); stA(1, 1, 0);
    asm volatile("s_waitcnt vmcnt(8)" ::: "memory");   // tile0 landed, 4 ht in flight
    __builtin_amdgcn_s_barrier();

    const int sl0 = (quad ^ (ln & 7)) * 8;        // kk=0 swizzled chunk (shorts)
    const int sl1 = ((4 + quad) ^ (ln & 7)) * 8;  // kk=1

#define GVM(n_) asm volatile("s_waitcnt vmcnt(" #n_ ")" ::: "memory")
#define GLDB(c_)                                                              \
    {                                                                         \
        _Pragma("unroll")                                                     \
        for (int j = 0; j < 4; ++j) {                                         \
            const int br_ = (wn * 64 + j * 16 + ln) * 64;                     \
            bfr[j][0] = *(const shortx8*)(&Bs[c_][br_ + sl0]);                \
            bfr[j][1] = *(const shortx8*)(&Bs[c_][br_ + sl1]);                \
        }                                                                     \
    }
#define GPH(c_, q_, STAGE_STMT, VM_STMT)                                      \
    {                                                                         \
        const int rb_ = (wm * 128 + (q_) * 32 + ln) * 64;                     \
        shortx8 af00 = *(const shortx8*)(&As[c_][rb_ + sl0]);                 \
        shortx8 af01 = *(const shortx8*)(&As[c_][rb_ + sl1]);                 \
        shortx8 af10 = *(const shortx8*)(&As[c_][rb_ + 1024 + sl0]);          \
        shortx8 af11 = *(const shortx8*)(&As[c_][rb_ + 1024 + sl1]);          \
        STAGE_STMT                                                            \
        asm volatile("" ::: "memory");                                        \
        __builtin_amdgcn_s_barrier();                                         \
        asm volatile("s_waitcnt lgkmcnt(0)" ::: "memory");                    \
        __builtin_amdgcn_s_setprio(1);                                        \
        _Pragma("unroll")                                                     \
        for (int j = 0; j < 4; ++j) {                                         \
            acc[(q_)*2][j]   = __builtin_amdgcn_mfma_f32_16x16x32_bf16(af00, bfr[j][0], acc[(q_)*2][j], 0, 0, 0);   \
            acc[(q_)*2][j]   = __builtin_amdgcn_mfma_f32_16x16x32_bf16(af01, bfr[j][1], acc[(q_)*2][j], 0, 0, 0);   \
            acc[(q_)*2+1][j] = __builtin_amdgcn_mfma_f32_16x16x32_bf16(af10, bfr[j][0], acc[(q_)*2+1][j], 0, 0, 0); \
            acc[(q_)*2+1][j] = __builtin_amdgcn_mfma_f32_16x16x32_bf16(af11, bfr[j][1], acc[(q_)*2+1][j], 0, 0, 0); \
        }                                                                     \
        __builtin_amdgcn_s_setprio(0);                                        \
        VM_STMT                                                               \
        asm volatile("" ::: "memory");                                        \
        __builtin_amdgcn_s_barrier();                                         \
    }

    const int NI = K >> 7;                        // 8 iters (2 K-tiles each)
    for (int I = 0; I < NI; ++I) {
        const int n = 2 * I;
        const bool L = (I == NI - 1);
        GLDB(0)
        GPH(0, 0, { stA(n + 1, 1, 1); }, {})
        GPH(0, 1, { if (!L) stB(n + 2, 0, 0); }, { if (L) { GVM(8); } else { GVM(10); } })
        GPH(0, 2, { if (!L) stB(n + 2, 0, 1); }, {})
        GPH(0, 3, { if (!L) stA(n + 2, 0, 0); }, { if (L) { GVM(2); } else { GVM(8); } })
        GLDB(1)
        GPH(1, 0, { if (!L) stA(n + 2, 0, 1); }, {})
        GPH(1, 1, { if (!L) stB(n + 3, 1, 0); }, { if (L) { GVM(0); } else { GVM(10); } })
        GPH(1, 2, { if (!L) stB(n + 3, 1, 1); }, {})
        GPH(1, 3, { if (!L) stA(n + 3, 1, 0); }, { if (!L) { GVM(8); } })
    }
#undef GPH
#undef GLDB
#undef GVM

    if (bn < 3072) {
        // q|k|qr block: row-major qcat, stride 3072
#pragma unroll
        for (int i = 0; i < 8; ++i)
#pragma unroll
            for (int j = 0; j < 4; ++j)
#pragma unroll
                for (int r = 0; r < 4; ++r) {
                    int row = bm + wm * 128 + i * 16 + quad * 4 + r;
                    int col = bn + wn * 64 + j * 16 + ln;
                    C[(size_t)row * 3072 + col] = f2bf(acc[i][j][r]);
                }
    } else {
        // KR block: write transposed directly to krT[b*1024+hd][l], 8B/lane/frag
        const int b = bm >> 11;                     // block-uniform (bm mult of 256)
        const int l0b = (bm & 2047) + wm * 128 + quad * 4;
#pragma unroll
        for (int i = 0; i < 8; ++i)
#pragma unroll
            for (int j = 0; j < 4; ++j) {
                const int hd = (bn - 3072) + wn * 64 + j * 16 + ln;
                const int l0 = l0b + i * 16;
                shortx4 o;
#pragma unroll
                for (int r = 0; r < 4; ++r) o[r] = (short)f2bf(acc[i][j][r]);
                *(shortx4*)(krT + ((size_t)(b * 1024 + hd)) * 2048 + l0) = o;
            }
    }
}

// ---------- GEMM 128x64 tiles (output proj), dbuf + bijective swizzle ----------
__global__ __launch_bounds__(256) void k_gemm_n64(const unsigned short* __restrict__ A,
                                                  const unsigned short* __restrict__ Bt,
                                                  float* __restrict__ C,
                                                  int N, int K) {
    __shared__ alignas(16) unsigned short As[2][128 * 32];
    __shared__ alignas(16) unsigned short Bs[2][64 * 32];
    const int t = threadIdx.x;
    const int lane = t & 63, wv = t >> 6;
    const int ln = lane & 15, quad = lane >> 4;
    const int bm = blockIdx.y * 128, bn = blockIdx.x * 64;

    floatx4 acc[2][4] = {};

    const int srow = t >> 2;
    const int sc = (t & 3) ^ ((srow >> 1) & 3);
    const unsigned short* ga0 = A + (size_t)(bm + srow) * K + sc * 8;
    const unsigned short* ga1 = ga0 + (size_t)64 * K;
    const unsigned short* gb0 = Bt + (size_t)(bn + srow) * K + sc * 8;

    gll16(ga0, &As[0][wv * 512]);
    gll16(ga1, &As[0][2048 + wv * 512]);
    gll16(gb0, &Bs[0][wv * 512]);

    const int sw = (ln >> 1) & 3;
    int cur = 0;
    for (int k0 = 0; k0 < K; k0 += 32, cur ^= 1) {
        __syncthreads();
        const int nk = k0 + 32;
        if (nk < K) {
            gll16(ga0 + nk, &As[cur ^ 1][wv * 512]);
            gll16(ga1 + nk, &As[cur ^ 1][2048 + wv * 512]);
            gll16(gb0 + nk, &Bs[cur ^ 1][wv * 512]);
        }
        shortx8 af[2], bfr[4];
#pragma unroll
        for (int i = 0; i < 2; ++i)
            af[i] = *(const shortx8*)(&As[cur][(wv * 32 + i * 16 + ln) * 32 + ((quad ^ sw) * 8)]);
#pragma unroll
        for (int j = 0; j < 4; ++j)
            bfr[j] = *(const shortx8*)(&Bs[cur][(j * 16 + ln) * 32 + ((quad ^ sw) * 8)]);
#pragma unroll
        for (int i = 0; i < 2; ++i)
#pragma unroll
            for (int j = 0; j < 4; ++j)
                acc[i][j] = __builtin_amdgcn_mfma_f32_16x16x32_bf16(af[i], bfr[j], acc[i][j], 0, 0, 0);
    }

#pragma unroll
    for (int i = 0; i < 2; ++i)
#pragma unroll
        for (int j = 0; j < 4; ++j)
#pragma unroll
            for (int r = 0; r < 4; ++r) {
                int row = bm + wv * 32 + i * 16 + quad * 4 + r;
                int col = bn + j * 16 + ln;
                C[(size_t)row * N + col] = acc[i][j][r];
            }
}

// ---------- fused causal attention + Hadamard: key-partitioned waves ----------
// FULL-RESIDENCY: 1024 one-tile blocks at 4 blocks/CU (launch_bounds(256,4)) —
// every block resident from t=0, 4 waves/SIMD. Under round-robin dispatch the 4
// co-resident blocks on a CU are the SAME head with qt in {u,15-u,16+u,31-u}
// (sum 66 for all u): perfect static balance + one 512KB K/KR set per CU (L2
// reuse). XCD pinning preserved: flat%8 == bh%8 for all of a head's blocks.
// K-loop: round-5 proven structure (one __syncthreads per tile, stage(kt+1)
// into the opposite buffer — DMA overlaps compute).
__global__ __launch_bounds__(256, 4) void k_attn(const unsigned short* __restrict__ qcat,
                                                 const unsigned short* __restrict__ krT,
                                                 unsigned short* __restrict__ ar) {
    __shared__ alignas(16) unsigned short Kl[2][64 * 64];  // [m][d] swizzled
    __shared__ alignas(16) unsigned short Rl[2][64 * 64];  // [d][m] swizzled
    __shared__ float Ls[4][4][16];                         // lsum partials [w][qc][ln]

    const int t = threadIdx.x;
    const int lane = t & 63, w = t >> 6;
    const int ln = lane & 15, quad = lane >> 4;
    const int flat = blockIdx.x;                           // 0..1023
    const int g = flat & 255, r4 = flat >> 8;              // CU slot, co-resident idx
    const int bh = g & 31, u = g >> 5;                     // head, balance key
    const int qt = (r4 == 0) ? u : (r4 == 1) ? 15 - u : (r4 == 2) ? 16 + u : 31 - u;
    const int b = bh >> 4, h = bh & 15;
    const int l0 = qt * 64;
    const size_t baserow = (size_t)b * 2048;

    // Q B-frags for ALL 4 q-blocks: col q = qc*16+ln, k(d) = quad*8+i (+32)
    shortx8 aq[4][2];
#pragma unroll
    for (int qc = 0; qc < 4; ++qc) {
        const unsigned short* qp =
            qcat + (baserow + l0 + qc * 16 + ln) * 3072 + h * 64 + quad * 8;
        aq[qc][0] = *(const shortx8*)(qp);
        aq[qc][1] = *(const shortx8*)(qp + 32);
    }

    floatx4 acc_o[4][4] = {};   // [qc][jd] partial over THIS wave's keys
    float lsum[4] = {0.f, 0.f, 0.f, 0.f};

    const int srow = t >> 3;
    const int sc = (t & 7) ^ (srow & 7);
    const unsigned short* gK = qcat + (baserow + srow) * 3072 + 1024 + h * 64 + sc * 8;
    const unsigned short* gR = krT + ((size_t)bh * 64 + srow) * 2048 + sc * 8;

    auto stage = [&](int kt, int buf) {
        gll16(gK + (size_t)(kt * 64) * 3072,      &Kl[buf][w * 512]);
        gll16(gK + (size_t)(kt * 64 + 32) * 3072, &Kl[buf][2048 + w * 512]);
        gll16(gR + kt * 64,                       &Rl[buf][w * 512]);
        gll16(gR + (size_t)32 * 2048 + kt * 64,   &Rl[buf][2048 + w * 512]);
    };

    stage(0, 0);
    const int swz = ln & 7;          // read-side swizzle key (rows stride 16: &7 == ln&7)
    const int krow = (w * 16 + ln) * 64;
    const int cmw = w * 2 + (quad >> 1);
    int cur = 0;
    for (int kt = 0; kt <= qt; ++kt, cur ^= 1) {
        __syncthreads();             // drains DMA; prev iter's LDS reads done
        if (kt < qt) stage(kt + 1, cur ^ 1);
        const unsigned short* Kc = Kl[cur];
        const unsigned short* Rc = Rl[cur];
        const bool diag = (kt == qt);

        // this wave's K fragments (keys w*16 + quad*4+r after MFMA)
        shortx8 kf0 = *(const shortx8*)(Kc + krow + ((quad ^ swz) * 8));
        shortx8 kf1 = *(const shortx8*)(Kc + krow + (((4 + quad) ^ swz) * 8));
        // this wave's KR A-frags, shared across all q-blocks
        shortx4 krf[4];
#pragma unroll
        for (int jd = 0; jd < 4; ++jd)
            krf[jd] = *(const shortx4*)(Rc + (jd * 16 + ln) * 64 +
                                        ((cmw ^ swz) * 8) + (quad & 1) * 4);

        const int keyb = kt * 64 + w * 16 + quad * 4;   // global key (+r)
        shortx4 pk[4];
#pragma unroll
        for (int qc = 0; qc < 4; ++qc) {
            floatx4 z = {0.f, 0.f, 0.f, 0.f};
            z = __builtin_amdgcn_mfma_f32_16x16x32_bf16(kf0, aq[qc][0], z, 0, 0, 0);
            z = __builtin_amdgcn_mfma_f32_16x16x32_bf16(kf1, aq[qc][1], z, 0, 0, 0);
            float e0 = exp2fast(z[0]);
            float e1 = exp2fast(z[1]);
            float e2 = exp2fast(z[2]);
            float e3 = exp2fast(z[3]);
            if (diag) {
                const int q = l0 + qc * 16 + ln;
                e0 = (keyb + 0 > q) ? 0.f : e0;
                e1 = (keyb + 1 > q) ? 0.f : e1;
                e2 = (keyb + 2 > q) ? 0.f : e2;
                e3 = (keyb + 3 > q) ? 0.f : e3;
            }
            lsum[qc] += (e0 + e1) + (e2 + e3);
            struct U2 { unsigned a, b; } u2{pkbf(e0, e1), pkbf(e2, e3)};
            pk[qc] = __builtin_bit_cast(shortx4, u2);
        }

        __builtin_amdgcn_s_setprio(1);       // T5: pure-MFMA PV cluster
#pragma unroll
        for (int qc = 0; qc < 4; ++qc)
#pragma unroll
            for (int jd = 0; jd < 4; ++jd)
                acc_o[qc][jd] = mfma16(krf[jd], pk[qc], acc_o[qc][jd]);
        __builtin_amdgcn_s_setprio(0);
    }

    // lsum: reduce over quads inside the wave, publish per-wave partial
#pragma unroll
    for (int qc = 0; qc < 4; ++qc) {
        float s = lsum[qc];
        s += __shfl_xor(s, 16);
        s += __shfl_xor(s, 32);
        lsum[qc] = s;
    }
    if (lane < 16) {
#pragma unroll
        for (int qc = 0; qc < 4; ++qc) Ls[w][qc][lane] = lsum[qc];
    }

    // cross-wave O^T reduction through LDS (fp32), tree: (2,3)->(0,1), 1->0
    __syncthreads();                  // loop reads done; Kl/Rl reusable; Ls visible
    float* redA = (float*)&Kl[0][0];  // 4096 floats
    float* redB = (float*)&Rl[0][0];  // 4096 floats
    if (w >= 2) {
        float* dst = (w == 2) ? redA : redB;
#pragma unroll
        for (int qc = 0; qc < 4; ++qc)
#pragma unroll
            for (int jd = 0; jd < 4; ++jd)
                *(floatx4*)(dst + ((qc * 4 + jd) * 64 + lane) * 4) = acc_o[qc][jd];
    }
    __syncthreads();
    if (w < 2) {
        const float* src = (w == 0) ? redA : redB;
#pragma unroll
        for (int qc = 0; qc < 4; ++qc)
#pragma unroll
            for (int jd = 0; jd < 4; ++jd)
                acc_o[qc][jd] += *(const floatx4*)(src + ((qc * 4 + jd) * 64 + lane) * 4);
    }
    __syncthreads();
    if (w == 1) {
#pragma unroll
        for (int qc = 0; qc < 4; ++qc)
#pragma unroll
            for (int jd = 0; jd < 4; ++jd)
                *(floatx4*)(redA + ((qc * 4 + jd) * 64 + lane) * 4) = acc_o[qc][jd];
    }
    __syncthreads();
    if (w == 0) {
        float inv[4];
#pragma unroll
        for (int qc = 0; qc < 4; ++qc)
            inv[qc] = 1.0f / (Ls[0][qc][ln] + Ls[1][qc][ln] + Ls[2][qc][ln] + Ls[3][qc][ln]);
#pragma unroll
        for (int qc = 0; qc < 4; ++qc) {
            const int q = l0 + qc * 16 + ln;
            const unsigned short* qr = qcat + (baserow + q) * 3072 + 2048 + h * 64;
            unsigned short* arow = ar + (baserow + q) * 1024 + h * 64;
#pragma unroll
            for (int jd = 0; jd < 4; ++jd) {
                floatx4 a = acc_o[qc][jd];
                a += *(const floatx4*)(redA + ((qc * 4 + jd) * 64 + lane) * 4);
                const int d0 = jd * 16 + quad * 4;
                shortx4 qv = *(const shortx4*)(qr + d0);
                shortx4 o;
#pragma unroll
                for (int r = 0; r < 4; ++r)
                    o[r] = (short)f2bf(a[r] * inv[qc] * bf2f((unsigned short)qv[r]));
                *(shortx4*)(arow + d0) = o;
            }
        }
    }
}

extern "C" void kernel_launch(void* const* d_in, const int* in_sizes, int n_in,
                              void* d_out, int out_size, void* d_ws, size_t ws_size,
                              hipStream_t stream) {
    const float* x   = (const float*)d_in[0];
    const float* wq  = (const float*)d_in[1];
    const float* wk  = (const float*)d_in[2];
    const float* wqr = (const float*)d_in[3];
    const float* wkr = (const float*)d_in[4];
    const float* wo  = (const float*)d_in[5];
    float* out = (float*)d_out;

    unsigned short* xb    = (unsigned short*)d_ws;
    unsigned short* wcatT = xb + (size_t)4096 * 1024;
    unsigned short* qcat  = wcatT + (size_t)4096 * 1024;      // [4096][3072]
    unsigned short* krT   = qcat + (size_t)4096 * 3072;       // [32*64][2048], 8 MB
    unsigned short* wotT  = krT + (size_t)32 * 64 * 2048;     // 2 MB; total 50 MB
    unsigned short* arb   = xb;      // xb dead after proj GEMM

    k_cvt_all<<<5376, 256, 0, stream>>>(x, wq, wk, wqr, wkr, wo, xb, wcatT, wotT);
    k_gemm_bt256<<<256, 512, 0, stream>>>(xb, wcatT, qcat, krT, 1024);
    k_attn<<<1024, 256, 0, stream>>>(qcat, krT, arb);
    k_gemm_n64<<<dim3(16, 32), 256, 0, stream>>>(arb, wotT, out, 1024, 1024);
}

// Round 9
// 181.005 us; speedup vs baseline: 1.2265x; 1.2265x over previous
//
#include <hip/hip_runtime.h>
#include <stdint.h>

// B=2, L=2048, DM=1024, H=16, D=64
// ws layout (50 MB exactly):
//   xb    bf16[4096][1024]   x converted           (reused as arb after proj GEMM)
//   wcatT bf16[4096][1024]   [wq*0.125*log2e|wk|wqr|wkr]^T
//   qcat  bf16[4096][3072]   q|k|qr col blocks (stride 3072)
//   krT   bf16[32*64][2048]  kr transposed [b*1024+h*64+d][l] — written DIRECTLY
//                            by the proj GEMM epilogue (bn>=3072 tiles)
//   wotT  bf16[1024][1024]   wo^T

typedef __attribute__((ext_vector_type(4))) float floatx4;
typedef __attribute__((ext_vector_type(8))) short shortx8;
typedef __attribute__((ext_vector_type(4))) short shortx4;

__device__ __forceinline__ unsigned short f2bf(float f) {
    unsigned u = __float_as_uint(f);
    u += 0x7fffu + ((u >> 16) & 1u);   // RNE
    return (unsigned short)(u >> 16);
}
__device__ __forceinline__ float bf2f(unsigned short s) {
    return __uint_as_float(((unsigned)s) << 16);
}
__device__ __forceinline__ float exp2fast(float x) {
#if __has_builtin(__builtin_amdgcn_exp2f)
    return __builtin_amdgcn_exp2f(x);
#else
    return __expf(x * 0.69314718056f);
#endif
}
// pack hi16(e0),hi16(e1) -> one dword via v_perm (bf16 truncation, 1 VALU op)
__device__ __forceinline__ unsigned pkbf(float e0, float e1) {
    return __builtin_amdgcn_perm(__float_as_uint(e1), __float_as_uint(e0), 0x07060302u);
}
// PV MFMA: D += A(4 bf16, k=quad*4+i) * B(4 bf16, k=quad*4+i)
__device__ __forceinline__ floatx4 mfma16(shortx4 a, shortx4 b, floatx4 c) {
#if __has_builtin(__builtin_amdgcn_mfma_f32_16x16x16bf16_1k)
    return __builtin_amdgcn_mfma_f32_16x16x16bf16_1k(a, b, c, 0, 0, 0);
#else
    shortx8 a8 = {a[0], a[1], a[2], a[3], 0, 0, 0, 0};
    shortx8 b8 = {b[0], b[1], b[2], b[3], 0, 0, 0, 0};
    return __builtin_amdgcn_mfma_f32_16x16x32_bf16(a8, b8, c, 0, 0, 0);
#endif
}
// async global->LDS, 16B/lane; lds dest = wave-uniform base + lane*16
__device__ __forceinline__ void gll16(const void* g, void* l) {
    __builtin_amdgcn_global_load_lds(
        (const __attribute__((address_space(1))) unsigned int*)g,
        (__attribute__((address_space(3))) unsigned int*)l, 16, 0, 0);
}

// ---------- x -> bf16 (coalesced) ----------
__global__ void k_cvt_x(const float* __restrict__ x, unsigned short* __restrict__ xb) {
    int i = (blockIdx.x * 256 + threadIdx.x) * 4;
    float4 v = *(const float4*)(x + i);
    ushort4 o;
    o.x = f2bf(v.x); o.y = f2bf(v.y); o.z = f2bf(v.z); o.w = f2bf(v.w);
    *(ushort4*)(xb + i) = o;
}

// ---------- all 5 weights: fp32 [k][n] -> bf16 [n][k], LDS-tiled; z selects W ----------
__global__ __launch_bounds__(256) void k_cvt_w5(const float* __restrict__ wq,
                                                const float* __restrict__ wk,
                                                const float* __restrict__ wqr,
                                                const float* __restrict__ wkr,
                                                const float* __restrict__ wo,
                                                unsigned short* __restrict__ wcatT,
                                                unsigned short* __restrict__ wotT) {
    __shared__ unsigned short Tl[64 * 65];
    const int t = threadIdx.x;
    const int kt = blockIdx.x * 64, nt = blockIdx.y * 64;
    const int z = blockIdx.z;
    const float* W = (z == 0) ? wq : (z == 1) ? wk : (z == 2) ? wqr : (z == 3) ? wkr : wo;
    unsigned short* outT = (z < 4) ? (wcatT + (size_t)z * 1024 * 1024) : wotT;
    // fold SDPA scale AND log2(e) into wq: scores in log2 domain, p = 2^z
    const float scale = (z == 0) ? 0.18033688f : 1.0f;   // 0.125 * 1.44269504
    {
        const int kl = t >> 3, nc = (t & 7) * 8;
        const float* src = W + (size_t)(kt + kl) * 1024 + nt + nc;
        float a[8], b[8];
        *(float4*)(a)     = *(const float4*)(src);
        *(float4*)(a + 4) = *(const float4*)(src + 4);
        *(float4*)(b)     = *(const float4*)(src + 32 * 1024);
        *(float4*)(b + 4) = *(const float4*)(src + 32 * 1024 + 4);
#pragma unroll
        for (int i = 0; i < 8; ++i) {
            Tl[kl * 65 + nc + i]        = f2bf(a[i] * scale);
            Tl[(kl + 32) * 65 + nc + i] = f2bf(b[i] * scale);
        }
    }
    __syncthreads();
    {
        const int n = t >> 2, kc = (t & 3) * 16;
        shortx8 o0, o1;
#pragma unroll
        for (int i = 0; i < 8; ++i) {
            o0[i] = (short)Tl[(kc + i) * 65 + n];
            o1[i] = (short)Tl[(kc + 8 + i) * 65 + n];
        }
        unsigned short* dst = outT + (size_t)(nt + n) * 1024 + kt + kc;
        *(shortx8*)(dst)     = o0;
        *(shortx8*)(dst + 8) = o1;
    }
}

// ---------- GEMM 256x256x(BK=64): 8-phase, 2-dbuf, counted-vmcnt pipeline ----------
// (proven <42.4 us, refcheck'd — rounds 5-8)
__global__ __launch_bounds__(512, 1) void k_gemm_bt256(const unsigned short* __restrict__ A,
                                                       const unsigned short* __restrict__ Bt,
                                                       unsigned short* __restrict__ C,
                                                       unsigned short* __restrict__ krT,
                                                       int K) {
    __shared__ alignas(16) unsigned short As[2][256 * 64];   // 64 KiB
    __shared__ alignas(16) unsigned short Bs[2][256 * 64];   // 64 KiB
    const int t = threadIdx.x;
    const int lane = t & 63, w = t >> 6;
    const int ln = lane & 15, quad = lane >> 4;
    const int wm = w >> 2, wn = w & 3;          // 2x4 wave grid, per-wave 128x64 out
    // XCD-pinned: each XCD owns a 4x8 region of the 16x16 tile grid
    const int flat = blockIdx.x;
    const int xcd = flat & 7, idx = flat >> 3;
    const int bm = ((xcd >> 1) * 4 + (idx >> 3)) * 256;
    const int bn = ((xcd & 1) * 8 + (idx & 7)) * 256;

    floatx4 acc[8][4] = {};
    shortx8 bfr[4][2];

    // staging: wave-linear LDS dest, pre-swizzled global source chunk
    const int srow8 = w * 8 + (lane >> 3);        // 0..63
    const int sc8 = (lane & 7) ^ (lane >> 3);     // involution: chunk ^ (row&7)
    const unsigned short* gA2 = A + (size_t)(bm + srow8) * K + sc8 * 8;
    const unsigned short* gB2 = Bt + (size_t)(bn + srow8) * K + sc8 * 8;
    const int wb = w * 512;                       // wave LDS slab (shorts)

    auto stA = [&](int kt, int c, int qr) {       // qr: 0=alpha, 1=beta
        const unsigned short* s = gA2 + (size_t)(qr * 64) * K + kt * 64;
        gll16(s,                   &As[c][(qr * 64) * 64 + wb]);
        gll16(s + (size_t)128 * K, &As[c][(128 + qr * 64) * 64 + wb]);
    };
    auto stB = [&](int kt, int c, int h) {        // h: 0=rows 0-127, 1=rows 128-255
        const unsigned short* s = gB2 + (size_t)(h * 128) * K + kt * 64;
        gll16(s,                  &Bs[c][(h * 128) * 64 + wb]);
        gll16(s + (size_t)64 * K, &Bs[c][(h * 128 + 64) * 64 + wb]);
    };

    // prologue: Bt0,Bb0,Aa0,Ab0,Bt1,Bb1,Aa1 (7 half-tiles, 14 loads/wave)
    stB(0, 0, 0); stB(0, 0, 1); stA(0, 0, 0); stA(0, 0, 1);
    stB(1, 1, 0); stB(1, 1, 1); stA(1, 1, 0);
    asm volatile("s_waitcnt vmcnt(8)" ::: "memory");   // tile0 landed, 4 ht in flight
    __builtin_amdgcn_s_barrier();

    const int sl0 = (quad ^ (ln & 7)) * 8;        // kk=0 swizzled chunk (shorts)
    const int sl1 = ((4 + quad) ^ (ln & 7)) * 8;  // kk=1

#define GVM(n_) asm volatile("s_waitcnt vmcnt(" #n_ ")" ::: "memory")
#define GLDB(c_)                                                              \
    {                                                                         \
        _Pragma("unroll")                                                     \
        for (int j = 0; j < 4; ++j) {                                         \
            const int br_ = (wn * 64 + j * 16 + ln) * 64;                     \
            bfr[j][0] = *(const shortx8*)(&Bs[c_][br_ + sl0]);                \
            bfr[j][1] = *(const shortx8*)(&Bs[c_][br_ + sl1]);                \
        }                                                                     \
    }
#define GPH(c_, q_, STAGE_STMT, VM_STMT)                                      \
    {                                                                         \
        const int rb_ = (wm * 128 + (q_) * 32 + ln) * 64;                     \
        shortx8 af00 = *(const shortx8*)(&As[c_][rb_ + sl0]);                 \
        shortx8 af01 = *(const shortx8*)(&As[c_][rb_ + sl1]);                 \
        shortx8 af10 = *(const shortx8*)(&As[c_][rb_ + 1024 + sl0]);          \
        shortx8 af11 = *(const shortx8*)(&As[c_][rb_ + 1024 + sl1]);          \
        STAGE_STMT                                                            \
        asm volatile("" ::: "memory");                                        \
        __builtin_amdgcn_s_barrier();                                         \
        asm volatile("s_waitcnt lgkmcnt(0)" ::: "memory");                    \
        __builtin_amdgcn_s_setprio(1);                                        \
        _Pragma("unroll")                                                     \
        for (int j = 0; j < 4; ++j) {                                         \
            acc[(q_)*2][j]   = __builtin_amdgcn_mfma_f32_16x16x32_bf16(af00, bfr[j][0], acc[(q_)*2][j], 0, 0, 0);   \
            acc[(q_)*2][j]   = __builtin_amdgcn_mfma_f32_16x16x32_bf16(af01, bfr[j][1], acc[(q_)*2][j], 0, 0, 0);   \
            acc[(q_)*2+1][j] = __builtin_amdgcn_mfma_f32_16x16x32_bf16(af10, bfr[j][0], acc[(q_)*2+1][j], 0, 0, 0); \
            acc[(q_)*2+1][j] = __builtin_amdgcn_mfma_f32_16x16x32_bf16(af11, bfr[j][1], acc[(q_)*2+1][j], 0, 0, 0); \
        }                                                                     \
        __builtin_amdgcn_s_setprio(0);                                        \
        VM_STMT                                                               \
        asm volatile("" ::: "memory");                                        \
        __builtin_amdgcn_s_barrier();                                         \
    }

    const int NI = K >> 7;                        // 8 iters (2 K-tiles each)
    for (int I = 0; I < NI; ++I) {
        const int n = 2 * I;
        const bool L = (I == NI - 1);
        GLDB(0)
        GPH(0, 0, { stA(n + 1, 1, 1); }, {})
        GPH(0, 1, { if (!L) stB(n + 2, 0, 0); }, { if (L) { GVM(8); } else { GVM(10); } })
        GPH(0, 2, { if (!L) stB(n + 2, 0, 1); }, {})
        GPH(0, 3, { if (!L) stA(n + 2, 0, 0); }, { if (L) { GVM(2); } else { GVM(8); } })
        GLDB(1)
        GPH(1, 0, { if (!L) stA(n + 2, 0, 1); }, {})
        GPH(1, 1, { if (!L) stB(n + 3, 1, 0); }, { if (L) { GVM(0); } else { GVM(10); } })
        GPH(1, 2, { if (!L) stB(n + 3, 1, 1); }, {})
        GPH(1, 3, { if (!L) stA(n + 3, 1, 0); }, { if (!L) { GVM(8); } })
    }
#undef GPH
#undef GLDB
#undef GVM

    if (bn < 3072) {
        // q|k|qr block: row-major qcat, stride 3072
#pragma unroll
        for (int i = 0; i < 8; ++i)
#pragma unroll
            for (int j = 0; j < 4; ++j)
#pragma unroll
                for (int r = 0; r < 4; ++r) {
                    int row = bm + wm * 128 + i * 16 + quad * 4 + r;
                    int col = bn + wn * 64 + j * 16 + ln;
                    C[(size_t)row * 3072 + col] = f2bf(acc[i][j][r]);
                }
    } else {
        // KR block: write transposed directly to krT[b*1024+hd][l], 8B/lane/frag
        const int b = bm >> 11;                     // block-uniform (bm mult of 256)
        const int l0b = (bm & 2047) + wm * 128 + quad * 4;
#pragma unroll
        for (int i = 0; i < 8; ++i)
#pragma unroll
            for (int j = 0; j < 4; ++j) {
                const int hd = (bn - 3072) + wn * 64 + j * 16 + ln;
                const int l0 = l0b + i * 16;
                shortx4 o;
#pragma unroll
                for (int r = 0; r < 4; ++r) o[r] = (short)f2bf(acc[i][j][r]);
                *(shortx4*)(krT + ((size_t)(b * 1024 + hd)) * 2048 + l0) = o;
            }
    }
}

// ---------- GEMM 128x64 tiles (output proj), dbuf + bijective swizzle ----------
__global__ __launch_bounds__(256) void k_gemm_n64(const unsigned short* __restrict__ A,
                                                  const unsigned short* __restrict__ Bt,
                                                  float* __restrict__ C,
                                                  int N, int K) {
    __shared__ alignas(16) unsigned short As[2][128 * 32];
    __shared__ alignas(16) unsigned short Bs[2][64 * 32];
    const int t = threadIdx.x;
    const int lane = t & 63, wv = t >> 6;
    const int ln = lane & 15, quad = lane >> 4;
    const int bm = blockIdx.y * 128, bn = blockIdx.x * 64;

    floatx4 acc[2][4] = {};

    const int srow = t >> 2;
    const int sc = (t & 3) ^ ((srow >> 1) & 3);
    const unsigned short* ga0 = A + (size_t)(bm + srow) * K + sc * 8;
    const unsigned short* ga1 = ga0 + (size_t)64 * K;
    const unsigned short* gb0 = Bt + (size_t)(bn + srow) * K + sc * 8;

    gll16(ga0, &As[0][wv * 512]);
    gll16(ga1, &As[0][2048 + wv * 512]);
    gll16(gb0, &Bs[0][wv * 512]);

    const int sw = (ln >> 1) & 3;
    int cur = 0;
    for (int k0 = 0; k0 < K; k0 += 32, cur ^= 1) {
        __syncthreads();
        const int nk = k0 + 32;
        if (nk < K) {
            gll16(ga0 + nk, &As[cur ^ 1][wv * 512]);
            gll16(ga1 + nk, &As[cur ^ 1][2048 + wv * 512]);
            gll16(gb0 + nk, &Bs[cur ^ 1][wv * 512]);
        }
        shortx8 af[2], bfr[4];
#pragma unroll
        for (int i = 0; i < 2; ++i)
            af[i] = *(const shortx8*)(&As[cur][(wv * 32 + i * 16 + ln) * 32 + ((quad ^ sw) * 8)]);
#pragma unroll
        for (int j = 0; j < 4; ++j)
            bfr[j] = *(const shortx8*)(&Bs[cur][(j * 16 + ln) * 32 + ((quad ^ sw) * 8)]);
#pragma unroll
        for (int i = 0; i < 2; ++i)
#pragma unroll
            for (int j = 0; j < 4; ++j)
                acc[i][j] = __builtin_amdgcn_mfma_f32_16x16x32_bf16(af[i], bfr[j], acc[i][j], 0, 0, 0);
    }

#pragma unroll
    for (int i = 0; i < 2; ++i)
#pragma unroll
        for (int j = 0; j < 4; ++j)
#pragma unroll
            for (int r = 0; r < 4; ++r) {
                int row = bm + wv * 32 + i * 16 + quad * 4 + r;
                int col = bn + j * 16 + ln;
                C[(size_t)row * N + col] = acc[i][j][r];
            }
}

// ---------- fused causal attention + Hadamard: key-partitioned waves ----------
// Best-measured configuration (182.4 us total): snake qt mapping, XCD-pinned
// heads, launch_bounds(256,2) — allocator free (VGPR ~104, no spill), HW can
// still co-schedule up to 4 blocks/CU. One __syncthreads per K-tile; stage(kt+1)
// into the opposite buffer overlaps DMA with compute.
__global__ __launch_bounds__(256, 2) void k_attn(const unsigned short* __restrict__ qcat,
                                                 const unsigned short* __restrict__ krT,
                                                 unsigned short* __restrict__ ar) {
    __shared__ alignas(16) unsigned short Kl[2][64 * 64];  // [m][d] swizzled
    __shared__ alignas(16) unsigned short Rl[2][64 * 64];  // [d][m] swizzled
    __shared__ float Ls[4][4][16];                         // lsum partials [w][qc][ln]

    const int t = threadIdx.x;
    const int lane = t & 63, w = t >> 6;
    const int ln = lane & 15, quad = lane >> 4;
    const int flat = blockIdx.x;
    const int bh = (flat & 7) * 4 + ((flat >> 3) & 3);     // XCD-pinned head
    const int qts = flat >> 5;                             // 0..31
    const int qt = (qts & 1) ? 31 - (qts >> 1) : (qts >> 1);
    const int b = bh >> 4, h = bh & 15;
    const int l0 = qt * 64;
    const size_t baserow = (size_t)b * 2048;

    // Q B-frags for ALL 4 q-blocks: col q = qc*16+ln, k(d) = quad*8+i (+32)
    shortx8 aq[4][2];
#pragma unroll
    for (int qc = 0; qc < 4; ++qc) {
        const unsigned short* qp =
            qcat + (baserow + l0 + qc * 16 + ln) * 3072 + h * 64 + quad * 8;
        aq[qc][0] = *(const shortx8*)(qp);
        aq[qc][1] = *(const shortx8*)(qp + 32);
    }

    floatx4 acc_o[4][4] = {};   // [qc][jd] partial over THIS wave's keys
    float lsum[4] = {0.f, 0.f, 0.f, 0.f};

    const int srow = t >> 3;
    const int sc = (t & 7) ^ (srow & 7);
    const unsigned short* gK = qcat + (baserow + srow) * 3072 + 1024 + h * 64 + sc * 8;
    const unsigned short* gR = krT + ((size_t)bh * 64 + srow) * 2048 + sc * 8;

    auto stage = [&](int kt, int buf) {
        gll16(gK + (size_t)(kt * 64) * 3072,      &Kl[buf][w * 512]);
        gll16(gK + (size_t)(kt * 64 + 32) * 3072, &Kl[buf][2048 + w * 512]);
        gll16(gR + kt * 64,                       &Rl[buf][w * 512]);
        gll16(gR + (size_t)32 * 2048 + kt * 64,   &Rl[buf][2048 + w * 512]);
    };

    stage(0, 0);
    const int swz = ln & 7;          // read-side swizzle key (rows stride 16: &7 == ln&7)
    const int krow = (w * 16 + ln) * 64;
    const int cmw = w * 2 + (quad >> 1);
    int cur = 0;
    for (int kt = 0; kt <= qt; ++kt, cur ^= 1) {
        __syncthreads();             // drains DMA; prev iter's LDS reads done
        if (kt < qt) stage(kt + 1, cur ^ 1);
        const unsigned short* Kc = Kl[cur];
        const unsigned short* Rc = Rl[cur];
        const bool diag = (kt == qt);

        // this wave's K fragments (keys w*16 + quad*4+r after MFMA)
        shortx8 kf0 = *(const shortx8*)(Kc + krow + ((quad ^ swz) * 8));
        shortx8 kf1 = *(const shortx8*)(Kc + krow + (((4 + quad) ^ swz) * 8));
        // this wave's KR A-frags, shared across all q-blocks
        shortx4 krf[4];
#pragma unroll
        for (int jd = 0; jd < 4; ++jd)
            krf[jd] = *(const shortx4*)(Rc + (jd * 16 + ln) * 64 +
                                        ((cmw ^ swz) * 8) + (quad & 1) * 4);

        const int keyb = kt * 64 + w * 16 + quad * 4;   // global key (+r)
        shortx4 pk[4];
#pragma unroll
        for (int qc = 0; qc < 4; ++qc) {
            floatx4 z = {0.f, 0.f, 0.f, 0.f};
            z = __builtin_amdgcn_mfma_f32_16x16x32_bf16(kf0, aq[qc][0], z, 0, 0, 0);
            z = __builtin_amdgcn_mfma_f32_16x16x32_bf16(kf1, aq[qc][1], z, 0, 0, 0);
            float e0 = exp2fast(z[0]);
            float e1 = exp2fast(z[1]);
            float e2 = exp2fast(z[2]);
            float e3 = exp2fast(z[3]);
            if (diag) {
                const int q = l0 + qc * 16 + ln;
                e0 = (keyb + 0 > q) ? 0.f : e0;
                e1 = (keyb + 1 > q) ? 0.f : e1;
                e2 = (keyb + 2 > q) ? 0.f : e2;
                e3 = (keyb + 3 > q) ? 0.f : e3;
            }
            lsum[qc] += (e0 + e1) + (e2 + e3);
            struct U2 { unsigned a, b; } u{pkbf(e0, e1), pkbf(e2, e3)};
            pk[qc] = __builtin_bit_cast(shortx4, u);
        }

        __builtin_amdgcn_s_setprio(1);       // T5: pure-MFMA PV cluster
#pragma unroll
        for (int qc = 0; qc < 4; ++qc)
#pragma unroll
            for (int jd = 0; jd < 4; ++jd)
                acc_o[qc][jd] = mfma16(krf[jd], pk[qc], acc_o[qc][jd]);
        __builtin_amdgcn_s_setprio(0);
    }

    // lsum: reduce over quads inside the wave, publish per-wave partial
#pragma unroll
    for (int qc = 0; qc < 4; ++qc) {
        float s = lsum[qc];
        s += __shfl_xor(s, 16);
        s += __shfl_xor(s, 32);
        lsum[qc] = s;
    }
    if (lane < 16) {
#pragma unroll
        for (int qc = 0; qc < 4; ++qc) Ls[w][qc][lane] = lsum[qc];
    }

    // cross-wave O^T reduction through LDS (fp32), tree: (2,3)->(0,1), 1->0
    __syncthreads();                  // loop reads done; Kl/Rl reusable; Ls visible
    float* redA = (float*)&Kl[0][0];  // 4096 floats
    float* redB = (float*)&Rl[0][0];  // 4096 floats
    if (w >= 2) {
        float* dst = (w == 2) ? redA : redB;
#pragma unroll
        for (int qc = 0; qc < 4; ++qc)
#pragma unroll
            for (int jd = 0; jd < 4; ++jd)
                *(floatx4*)(dst + ((qc * 4 + jd) * 64 + lane) * 4) = acc_o[qc][jd];
    }
    __syncthreads();
    if (w < 2) {
        const float* src = (w == 0) ? redA : redB;
#pragma unroll
        for (int qc = 0; qc < 4; ++qc)
#pragma unroll
            for (int jd = 0; jd < 4; ++jd)
                acc_o[qc][jd] += *(const floatx4*)(src + ((qc * 4 + jd) * 64 + lane) * 4);
    }
    __syncthreads();
    if (w == 1) {
#pragma unroll
        for (int qc = 0; qc < 4; ++qc)
#pragma unroll
            for (int jd = 0; jd < 4; ++jd)
                *(floatx4*)(redA + ((qc * 4 + jd) * 64 + lane) * 4) = acc_o[qc][jd];
    }
    __syncthreads();
    if (w == 0) {
        float inv[4];
#pragma unroll
        for (int qc = 0; qc < 4; ++qc)
            inv[qc] = 1.0f / (Ls[0][qc][ln] + Ls[1][qc][ln] + Ls[2][qc][ln] + Ls[3][qc][ln]);
#pragma unroll
        for (int qc = 0; qc < 4; ++qc) {
            const int q = l0 + qc * 16 + ln;
            const unsigned short* qr = qcat + (baserow + q) * 3072 + 2048 + h * 64;
            unsigned short* arow = ar + (baserow + q) * 1024 + h * 64;
#pragma unroll
            for (int jd = 0; jd < 4; ++jd) {
                floatx4 a = acc_o[qc][jd];
                a += *(const floatx4*)(redA + ((qc * 4 + jd) * 64 + lane) * 4);
                const int d0 = jd * 16 + quad * 4;
                shortx4 qv = *(const shortx4*)(qr + d0);
                shortx4 o;
#pragma unroll
                for (int r = 0; r < 4; ++r)
                    o[r] = (short)f2bf(a[r] * inv[qc] * bf2f((unsigned short)qv[r]));
                *(shortx4*)(arow + d0) = o;
            }
        }
    }
}

extern "C" void kernel_launch(void* const* d_in, const int* in_sizes, int n_in,
                              void* d_out, int out_size, void* d_ws, size_t ws_size,
                              hipStream_t stream) {
    const float* x   = (const float*)d_in[0];
    const float* wq  = (const float*)d_in[1];
    const float* wk  = (const float*)d_in[2];
    const float* wqr = (const float*)d_in[3];
    const float* wkr = (const float*)d_in[4];
    const float* wo  = (const float*)d_in[5];
    float* out = (float*)d_out;

    unsigned short* xb    = (unsigned short*)d_ws;
    unsigned short* wcatT = xb + (size_t)4096 * 1024;
    unsigned short* qcat  = wcatT + (size_t)4096 * 1024;      // [4096][3072]
    unsigned short* krT   = qcat + (size_t)4096 * 3072;       // [32*64][2048], 8 MB
    unsigned short* wotT  = krT + (size_t)32 * 64 * 2048;     // 2 MB; total 50 MB
    unsigned short* arb   = xb;      // xb dead after proj GEMM

    k_cvt_x<<<4096, 256, 0, stream>>>(x, xb);
    k_cvt_w5<<<dim3(16, 16, 5), 256, 0, stream>>>(wq, wk, wqr, wkr, wo, wcatT, wotT);
    k_gemm_bt256<<<256, 512, 0, stream>>>(xb, wcatT, qcat, krT, 1024);
    k_attn<<<1024, 256, 0, stream>>>(qcat, krT, arb);
    k_gemm_n64<<<dim3(16, 32), 256, 0, stream>>>(arb, wotT, out, 1024, 1024);
}